// Round 13
// baseline (906.167 us; speedup 1.0000x reference)
//
#include <hip/hip_runtime.h>
#include <math.h>

#define NC 256
#define CH3 768
#define HWSZ 16384

typedef __attribute__((ext_vector_type(8))) short short8;
typedef __attribute__((ext_vector_type(4))) float f32x4;
typedef __attribute__((ext_vector_type(4))) unsigned int u32x4;

// ---- shared (table) region ----
static const size_t OFF_TW1   = 0;
static const size_t OFF_TW2   = 32768;
static const size_t OFF_HM    = 65536;
static const size_t OFF_SCALE = 65600;
static const size_t OFF_SHIFT = 66624;
static const size_t OFF_PACK  = 67648;
static const size_t OFF_AW    = 182336;
static const size_t OFF_GNP   = 444480;
static const size_t SHARED_END= 446528;

// ---- per-batch region ----
// R_QKV: [0..2.1M) QfH u16, [2.1M..4.19M) QfL u16, [4.19M..8.39M) dead, [8.39M..12.58M) V fp32
// R_SCR: pre-dw qkv fp32 -> T split u16 planes [0..8.39M) -> U split planes in place ; Hn hi/lo at HNOFF
// R_H  : Bq packed (gemm in) -> Kn hi/lo u16 planes -> Bq2 packed (av out)
static const size_t R_QKV  = 0;
static const size_t R_SCR  = 12582912;
static const size_t R_H    = 25165824;
static const size_t R_PP   = 29360128;
static const size_t R_RP   = 30408704;
static const size_t R_ATTN = 31457280;
static const size_t R_ACOMB= 31473664;
static const size_t R_PS   = 31490048;
static const size_t R_RS   = 31506432;
static const size_t R_DWP  = 31522816;
static const size_t R_SSUM = 31532032;
static const size_t R_SALT = 31532800;
static const size_t R_SSQ  = 31533568;
static const size_t RSTRIDE= 31534336;
static const size_t HNOFF  = 8388608;       // floats into R_SCR

#define TDA_RH 0
#define TDA_RL 8192
#define TDA_IH 16384
#define TDA_IL 24576
#define ETA_RH 32768
#define ETA_RL 40960
#define ETA_IH 49152
#define ETA_IL 57344
#define STB_RH 65536
#define STB_RL 73728
#define STB_IH 81920
#define STB_IL 90112
#define STB_NIH 98304
#define STB_NIL 106496

#define AWQ_H 0
#define AWQ_L 98304
#define AWO_H 196608
#define AWO_L 229376

__device__ inline unsigned short b16rn(float x){
  unsigned u = __float_as_uint(x);
  return (unsigned short)((u + 0x7FFFu + ((u>>16)&1u)) >> 16);
}
__device__ inline unsigned int pk_hi(float x, float y){
  return (__float_as_uint(x)>>16) | (__float_as_uint(y) & 0xFFFF0000u);
}
__device__ inline unsigned int pk_lo(float x, float y){
  float xl = x - __uint_as_float(__float_as_uint(x) & 0xFFFF0000u);
  float yl = y - __uint_as_float(__float_as_uint(y) & 0xFFFF0000u);
  return (unsigned)b16rn(xl) | ((unsigned)b16rn(yl)<<16);
}
__device__ inline short8 ld8g(const unsigned int* p){ return *(const short8*)p; }
__device__ inline short8 ld8s(const unsigned short* p){ return *(const short8*)p; }
__device__ inline void wr_split(unsigned short* H, unsigned short* L, size_t o, float v){
  unsigned u = __float_as_uint(v);
  H[o] = (unsigned short)(u >> 16);
  L[o] = b16rn(v - __uint_as_float(u & 0xFFFF0000u));
}

// ---------------- tables ----------------
__global__ __launch_bounds__(256) void init_tables_k(float* __restrict__ ws){
  int idx = blockIdx.x*256 + threadIdx.x;
  float2* tw1 = (float2*)(ws + OFF_TW1);
  float2* tw2 = (float2*)(ws + OFF_TW2);
  unsigned int* pk = (unsigned int*)(ws + OFF_PACK);
  const double P2 = 6.283185307179586476925286766559005;
  int m = idx >> 7, k = idx & 127;
  double a2 = P2 * (double)(m*k) / 16384.0;
  tw1[idx] = make_float2((float)cos(a2), (float)(-sin(a2)));
  tw2[idx] = make_float2((float)cos(a2), (float)( sin(a2)));
  if (idx < 64){
    double acc = 0.0;
    for (int v = 1; v < 32; v++) acc += sin(P2 * (double)((v*idx) & 63) / 64.0);
    ws[OFF_HM + idx] = (float)(-acc / 32.0);
  }
  if (idx < 8192){
    int r = idx >> 6, kp = idx & 63;
    int k0 = 2*kp, k1 = 2*kp+1;
    double a0 = P2 * (double)((r*k0) & 127) / 128.0;
    double a1 = P2 * (double)((r*k1) & 127) / 128.0;
    float c0 = (float)cos(a0), c1 = (float)cos(a1);
    float s0 = (float)sin(a0), s1 = (float)sin(a1);
    pk[TDA_RH + idx] = pk_hi(c0, c1);  pk[TDA_RL + idx] = pk_lo(c0, c1);
    pk[TDA_IH + idx] = pk_hi(-s0,-s1); pk[TDA_IL + idx] = pk_lo(-s0,-s1);
    pk[ETA_RH + idx] = pk_hi(c0, c1);  pk[ETA_RL + idx] = pk_lo(c0, c1);
    pk[ETA_IH + idx] = pk_hi(s0, s1);  pk[ETA_IL + idx] = pk_lo(s0, s1);
    float sr0, si0, sr1, si1;
    {
      int d0 = (r - k0) & 127, d1 = (r - k1) & 127;
      if (d0 == 0){ sr0 = 64.f; si0 = 0.f; }
      else if ((d0 & 1) == 0){ sr0 = 0.f; si0 = 0.f; }
      else { double th = 3.1415926535897932384626 * (double)d0 / 128.0;
             sr0 = 1.f; si0 = (float)(cos(th)/sin(th)); }
      if (d1 == 0){ sr1 = 64.f; si1 = 0.f; }
      else if ((d1 & 1) == 0){ sr1 = 0.f; si1 = 0.f; }
      else { double th = 3.1415926535897932384626 * (double)d1 / 128.0;
             sr1 = 1.f; si1 = (float)(cos(th)/sin(th)); }
    }
    pk[STB_RH + idx]  = pk_hi(sr0, sr1);  pk[STB_RL + idx]  = pk_lo(sr0, sr1);
    pk[STB_IH + idx]  = pk_hi(si0, si1);  pk[STB_IL + idx]  = pk_lo(si0, si1);
    pk[STB_NIH + idx] = pk_hi(-si0,-si1); pk[STB_NIL + idx] = pk_lo(-si0,-si1);
  }
}

// ---------------- pack weights (once) ----------------
__global__ __launch_bounds__(256) void wpack_k(const float* __restrict__ wqkv, const float* __restrict__ wout,
                                               unsigned int* __restrict__ aw){
  int id = blockIdx.x*256 + threadIdx.x;
  int row = id >> 7, kp = id & 127;
  if (row < CH3){
    float v0 = wqkv[row*256 + 2*kp], v1 = wqkv[row*256 + 2*kp + 1];
    aw[AWQ_H + row*128 + kp] = pk_hi(v0, v1);
    aw[AWQ_L + row*128 + kp] = pk_lo(v0, v1);
  } else {
    int r2 = row - CH3;
    float v0 = wout[r2*256 + 2*kp], v1 = wout[r2*256 + 2*kp + 1];
    aw[AWO_H + r2*128 + kp] = pk_hi(v0, v1);
    aw[AWO_L + r2*128 + kp] = pk_lo(v0, v1);
  }
}

// ---------------- groupnorm stats ----------------
__global__ __launch_bounds__(256) void gn_part_k(const float* __restrict__ x, float2* __restrict__ part){
  int id = blockIdx.x;
  const float4* p = (const float4*)(x + (size_t)id*HWSZ);
  int tid = threadIdx.x;
  float s = 0.f, sq = 0.f;
  #pragma unroll
  for (int i = 0; i < 16; i++){
    float4 v = p[tid + i*256];
    s  += v.x+v.y+v.z+v.w;
    sq += v.x*v.x+v.y*v.y+v.z*v.z+v.w*v.w;
  }
  __shared__ float r1[256], r2[256];
  r1[tid]=s; r2[tid]=sq; __syncthreads();
  for (int off=128; off; off>>=1){
    if (tid<off){ r1[tid]+=r1[tid+off]; r2[tid]+=r2[tid+off]; }
    __syncthreads();
  }
  if (tid==0) part[id] = make_float2(r1[0], r2[0]);
}
__global__ __launch_bounds__(128) void gn_fin_k(const float2* __restrict__ part, const float* __restrict__ gw,
                                                const float* __restrict__ gb, float* __restrict__ scale,
                                                float* __restrict__ shift){
  int bg = threadIdx.x;
  int b = bg >> 5, g = bg & 31;
  float s = 0.f, sq = 0.f;
  #pragma unroll
  for (int i = 0; i < 8; i++){
    float2 v = part[b*NC + g*8 + i];
    s += v.x; sq += v.y;
  }
  const float n = 8.0f*HWSZ;
  float mu = s/n, var = sq/n - mu*mu;
  float rs = rsqrtf(var + 1e-5f);
  for (int i = 0; i < 8; i++){
    int ch = g*8 + i;
    float sc = rs * gw[ch];
    scale[b*NC + ch] = sc;
    shift[b*NC + ch] = gb[ch] - mu*sc;
  }
}

// ---------------- pack GN(x) into Bq planes ----------------
__global__ __launch_bounds__(256) void packx_k(const float* __restrict__ xbase, const float* __restrict__ scale,
                                               const float* __restrict__ shift, float* __restrict__ R0,
                                               size_t rstride){
  int bz = blockIdx.z;
  const float* xb = xbase + (size_t)bz*NC*HWSZ;
  const float* sc = scale + bz*NC;
  const float* sh = shift + bz*NC;
  unsigned int* BqH = (unsigned int*)(R0 + (size_t)bz*rstride + R_H);
  unsigned int* BqL = BqH + 2097152;
  int kb = blockIdx.y;
  int n = blockIdx.x*256 + threadIdx.x;
  float v[8];
  #pragma unroll
  for (int c = 0; c < 8; c++){
    int ch = kb*8 + c;
    v[c] = xb[(size_t)ch*HWSZ + n]*sc[ch] + sh[ch];
  }
  u32x4 h, l;
  #pragma unroll
  for (int q = 0; q < 4; q++){
    h[q] = pk_hi(v[2*q], v[2*q+1]);
    l[q] = pk_lo(v[2*q], v[2*q+1]);
  }
  *(u32x4*)&BqH[((size_t)kb*HWSZ + n)*4] = h;
  *(u32x4*)&BqL[((size_t)kb*HWSZ + n)*4] = l;
}

// ---------------- LDS-free packed split-bf16 MFMA GEMM, depth-1 register pipeline ----------------
__global__ __launch_bounds__(256) void gemm_pk(const unsigned int* __restrict__ Ah, const unsigned int* __restrict__ Al,
                                               const unsigned int* __restrict__ Bh0, const unsigned int* __restrict__ Bl0,
                                               const float* __restrict__ bias, float* __restrict__ C0,
                                               size_t bstride, size_t cstride){
  const unsigned int* Bh = Bh0 + (size_t)blockIdx.z*bstride;
  const unsigned int* Bl = Bl0 + (size_t)blockIdx.z*bstride;
  float* C = C0 + (size_t)blockIdx.z*cstride;
  int tid = threadIdx.x;
  int lane = tid & 63, wid = tid >> 6;
  int m0 = blockIdx.y*128, n0 = blockIdx.x*128;
  int wr = (wid>>1)*64, wc = (wid&1)*64;
  int lr = lane & 15, lk = lane >> 4;
  f32x4 acc[4][4] = {};
  size_t aoff[4], boff[4];
  #pragma unroll
  for (int i=0;i<4;i++) aoff[i] = (size_t)(m0 + wr + i*16 + lr)*128 + lk*4;
  #pragma unroll
  for (int j=0;j<4;j++) boff[j] = ((size_t)lk*HWSZ + n0 + wc + j*16 + lr)*4;
  short8 aH[2][4], aL[2][4], bH[2][4], bL[2][4];
  #pragma unroll
  for (int i=0;i<4;i++){ aH[0][i] = ld8g(Ah + aoff[i]); aL[0][i] = ld8g(Al + aoff[i]); }
  #pragma unroll
  for (int j=0;j<4;j++){ bH[0][j] = ld8g(Bh + boff[j]); bL[0][j] = ld8g(Bl + boff[j]); }
  #pragma unroll
  for (int kt = 0; kt < 8; kt++){
    int cur = kt & 1, nxt = cur ^ 1;
    if (kt < 7){
      size_t da = (size_t)(kt+1)*16;
      size_t db = (size_t)(kt+1)*4*HWSZ*4;
      #pragma unroll
      for (int i=0;i<4;i++){ aH[nxt][i] = ld8g(Ah + aoff[i] + da); aL[nxt][i] = ld8g(Al + aoff[i] + da); }
      #pragma unroll
      for (int j=0;j<4;j++){ bH[nxt][j] = ld8g(Bh + boff[j] + db); bL[nxt][j] = ld8g(Bl + boff[j] + db); }
    }
    #pragma unroll
    for (int i=0;i<4;i++)
      #pragma unroll
      for (int j=0;j<4;j++){
        acc[i][j] = __builtin_amdgcn_mfma_f32_16x16x32_bf16(aH[cur][i], bH[cur][j], acc[i][j], 0,0,0);
        acc[i][j] = __builtin_amdgcn_mfma_f32_16x16x32_bf16(aH[cur][i], bL[cur][j], acc[i][j], 0,0,0);
        acc[i][j] = __builtin_amdgcn_mfma_f32_16x16x32_bf16(aL[cur][i], bH[cur][j], acc[i][j], 0,0,0);
      }
  }
  #pragma unroll
  for (int i=0;i<4;i++){
    #pragma unroll
    for (int e=0;e<4;e++){
      int row = m0 + wr + i*16 + lk*4 + e;
      float bb = bias ? bias[row] : 0.0f;
      #pragma unroll
      for (int j=0;j<4;j++)
        C[(size_t)row*HWSZ + n0 + wc + j*16 + lr] = acc[i][j][e] + bb;
    }
  }
}

// ---------------- depthwise 3x3, tiled; epilogue packs Qf (flipped) / Kn planes / V fp32 ----------------
__global__ __launch_bounds__(256) void dwconv_tiled_k(float* __restrict__ R0, size_t rstride,
                                                      const float* __restrict__ wdw){
  float* Rb = R0 + (size_t)blockIdx.y*rstride;
  int blk = blockIdx.x;
  int ch = blk >> 2, sl = blk & 3;
  int h0 = sl*32;
  const float* in = Rb + R_SCR + (size_t)ch*HWSZ;
  float* part = Rb + R_DWP;
  float w[9];
  #pragma unroll
  for (int i=0;i<9;i++) w[i] = wdw[ch*9+i];
  __shared__ float tile[34][132];
  __shared__ float r0[256], r1[256], r2[256];
  int tid = threadIdx.x;
  #pragma unroll
  for (int i = 0; i < 5; i++){
    int id = tid + i*256;
    if (id < 1088){
      int r = id >> 5, c4 = id & 31;
      int gh = h0 - 1 + r;
      float4 v = (gh >= 0 && gh < 128) ? *(const float4*)&in[gh*128 + c4*4]
                                       : make_float4(0.f,0.f,0.f,0.f);
      *(float4*)&tile[r][c4*4] = v;
    }
  }
  __syncthreads();
  float s=0.f, sa=0.f, sq=0.f;
  #pragma unroll
  for (int it=0; it<4; it++){
    int idx = it*256 + tid;
    int lh = idx >> 5;
    int xq = idx & 31;
    int xb4 = xq*4;
    float o[4];
    #pragma unroll
    for (int e=0;e<4;e++){
      int xw = xb4 + e;
      float acc = 0.f;
      #pragma unroll
      for (int ky=0; ky<3; ky++){
        const float* tr = &tile[lh+ky][xw];
        if (xw > 0)   acc += tr[-1]*w[ky*3+0];
                      acc += tr[ 0]*w[ky*3+1];
        if (xw < 127) acc += tr[ 1]*w[ky*3+2];
      }
      o[e] = acc;
      s += acc; sq += acc*acc;
      sa += (e & 1) ? -acc : acc;
    }
    int sbase = (h0+lh)*128 + xb4;
    if (ch < 256){
      unsigned short* QHo = (unsigned short*)(Rb + R_QKV);
      unsigned short* QLo = (unsigned short*)(Rb + R_QKV + 2097152);
      size_t ro = (size_t)ch*HWSZ;
      #pragma unroll
      for (int e=0;e<4;e++){
        int sf = (16384 - (sbase+e)) & 16383;
        wr_split(QHo, QLo, ro + sf, o[e]);
      }
    } else if (ch < 512){
      unsigned short* KHo = (unsigned short*)(Rb + R_H);
      unsigned short* KLo = (unsigned short*)(Rb + R_H + 2097152);
      size_t ro = (size_t)(ch-256)*HWSZ;
      #pragma unroll
      for (int e=0;e<4;e++)
        wr_split(KHo, KLo, ro + sbase+e, o[e]);
    } else {
      *(float4*)&(Rb + R_QKV + (size_t)ch*HWSZ)[sbase] = make_float4(o[0],o[1],o[2],o[3]);
    }
  }
  r0[tid]=s; r1[tid]=sa; r2[tid]=sq; __syncthreads();
  for (int off=128; off; off>>=1){
    if (tid<off){ r0[tid]+=r0[tid+off]; r1[tid]+=r1[tid+off]; r2[tid]+=r2[tid+off]; }
    __syncthreads();
  }
  if (tid==0){ part[blk]=r0[0]; part[3072+blk]=r1[0]; part[6144+blk]=r2[0]; }
}

// ---------------- FFT stage 1 (MFMA): reads Kn planes, writes T split u16 planes [f0][row][b2] ----------------
__global__ __launch_bounds__(256) void fft1_mfma_k(const float* __restrict__ ws, float* __restrict__ R0,
                                                   size_t rstride){
  float* Rb = R0 + (size_t)blockIdx.y*rstride;
  const unsigned short* KH = (const unsigned short*)(Rb + R_H);
  const unsigned short* KL = (const unsigned short*)(Rb + R_H + 2097152);
  unsigned short* TRH = (unsigned short*)(Rb + R_SCR);
  unsigned short* TRL = TRH + 4194304;
  unsigned short* TIH = TRL + 4194304;
  unsigned short* TIL = TIH + 4194304;
  const unsigned int* PK = (const unsigned int*)(ws + OFF_PACK);
  const float2* tw1 = (const float2*)(ws + OFF_TW1);
  __shared__ unsigned int Bth[128][20], Btl[128][20];
  int tid = threadIdx.x;
  int lane = tid & 63, wid = tid >> 6;
  int wr = (wid>>1)*64, wc = (wid&1)*64;
  int lr = lane & 15, lk = lane >> 4;
  int row = blockIdx.x;
  f32x4 aR[4][4] = {}, aI[4][4] = {};
  int bc = tid & 127, grp = tid >> 7;
  for (int kt = 0; kt < 4; kt++){
    #pragma unroll
    for (int p=0;p<8;p++){
      int kp = grp*8 + p;
      int a = kt*32 + 2*kp;
      size_t o0 = (size_t)row*HWSZ + a*128 + bc;
      Bth[bc][kp] = (unsigned)KH[o0] | ((unsigned)KH[o0+128] << 16);
      Btl[bc][kp] = (unsigned)KL[o0] | ((unsigned)KL[o0+128] << 16);
    }
    __syncthreads();
    short8 bh[4], bl[4];
    #pragma unroll
    for (int j=0;j<4;j++){
      bh[j] = *(const short8*)&Bth[wc + j*16 + lr][lk*4];
      bl[j] = *(const short8*)&Btl[wc + j*16 + lr][lk*4];
    }
    #pragma unroll
    for (int i=0;i<4;i++){
      int off = (wr + i*16 + lr)*64 + kt*16 + lk*4;
      short8 ahR = ld8g(PK + TDA_RH + off), alR = ld8g(PK + TDA_RL + off);
      short8 ahI = ld8g(PK + TDA_IH + off), alI = ld8g(PK + TDA_IL + off);
      #pragma unroll
      for (int j=0;j<4;j++){
        aR[i][j] = __builtin_amdgcn_mfma_f32_16x16x32_bf16(ahR, bh[j], aR[i][j], 0,0,0);
        aR[i][j] = __builtin_amdgcn_mfma_f32_16x16x32_bf16(ahR, bl[j], aR[i][j], 0,0,0);
        aR[i][j] = __builtin_amdgcn_mfma_f32_16x16x32_bf16(alR, bh[j], aR[i][j], 0,0,0);
        aI[i][j] = __builtin_amdgcn_mfma_f32_16x16x32_bf16(ahI, bh[j], aI[i][j], 0,0,0);
        aI[i][j] = __builtin_amdgcn_mfma_f32_16x16x32_bf16(ahI, bl[j], aI[i][j], 0,0,0);
        aI[i][j] = __builtin_amdgcn_mfma_f32_16x16x32_bf16(alI, bh[j], aI[i][j], 0,0,0);
      }
    }
    __syncthreads();
  }
  #pragma unroll
  for (int i=0;i<4;i++)
    #pragma unroll
    for (int e=0;e<4;e++){
      int m = wr + i*16 + lk*4 + e;     // f0
      #pragma unroll
      for (int j=0;j<4;j++){
        int col = wc + j*16 + lr;       // b2
        float2 t = tw1[m*128 + col];
        float r = aR[i][j][e], im = aI[i][j][e];
        float vr = r*t.x - im*t.y, vi = r*t.y + im*t.x;
        size_t o = (size_t)m*32768 + row*128 + col;
        wr_split(TRH, TRL, o, vr);
        wr_split(TIH, TIL, o, vi);
      }
    }
}

// ---------------- FFT stage 2 (MFMA, LDS-free, barrier-free): U in place over T planes ----------------
// grid (512, zb): blockIdx.x = row*2 + mhalf. Reads T[f0 in half][row][b2]; writes U same rows coalesced.
__global__ __launch_bounds__(256) void fft2_mfma_k(const float* __restrict__ ws, float* __restrict__ R0,
                                                   size_t rstride){
  float* Rb = R0 + (size_t)blockIdx.y*rstride;
  unsigned short* TRH = (unsigned short*)(Rb + R_SCR);
  unsigned short* TRL = TRH + 4194304;
  unsigned short* TIH = TRL + 4194304;
  unsigned short* TIL = TIH + 4194304;
  const unsigned int* PK = (const unsigned int*)(ws + OFF_PACK);
  const float2* tw2 = (const float2*)(ws + OFF_TW2);
  int tid = threadIdx.x, lane = tid & 63, wid = tid >> 6;
  int row = blockIdx.x >> 1, mh = blockIdx.x & 1;
  int wr1 = (wid>>1)*32, wc1 = (wid&1)*64;
  int lr = lane & 15, lk = lane >> 4;
  f32x4 aR[2][4] = {}, aI[2][4] = {};
  size_t aoff[2];
  #pragma unroll
  for (int i=0;i<2;i++) aoff[i] = (size_t)(mh*64 + wr1 + i*16 + lr)*32768 + (size_t)row*128 + lk*8;
  #pragma unroll
  for (int kt = 0; kt < 4; kt++){
    short8 ahR[2], alR[2], ahI[2], alI[2];
    #pragma unroll
    for (int i=0;i<2;i++){
      size_t o = aoff[i] + kt*32;
      ahR[i] = ld8s(TRH + o); alR[i] = ld8s(TRL + o);
      ahI[i] = ld8s(TIH + o); alI[i] = ld8s(TIL + o);
    }
    #pragma unroll
    for (int j=0;j<4;j++){
      int boff = (wc1 + j*16 + lr)*64 + kt*16 + lk*4;
      short8 bhR = ld8g(PK + STB_RH + boff), blR = ld8g(PK + STB_RL + boff);
      short8 bhI = ld8g(PK + STB_IH + boff), blI = ld8g(PK + STB_IL + boff);
      short8 bhN = ld8g(PK + STB_NIH + boff), blN = ld8g(PK + STB_NIL + boff);
      #pragma unroll
      for (int i=0;i<2;i++){
        aR[i][j] = __builtin_amdgcn_mfma_f32_16x16x32_bf16(ahR[i], bhR, aR[i][j], 0,0,0);
        aR[i][j] = __builtin_amdgcn_mfma_f32_16x16x32_bf16(ahR[i], blR, aR[i][j], 0,0,0);
        aR[i][j] = __builtin_amdgcn_mfma_f32_16x16x32_bf16(alR[i], bhR, aR[i][j], 0,0,0);
        aR[i][j] = __builtin_amdgcn_mfma_f32_16x16x32_bf16(ahI[i], bhN, aR[i][j], 0,0,0);
        aR[i][j] = __builtin_amdgcn_mfma_f32_16x16x32_bf16(ahI[i], blN, aR[i][j], 0,0,0);
        aR[i][j] = __builtin_amdgcn_mfma_f32_16x16x32_bf16(alI[i], bhN, aR[i][j], 0,0,0);
        aI[i][j] = __builtin_amdgcn_mfma_f32_16x16x32_bf16(ahR[i], bhI, aI[i][j], 0,0,0);
        aI[i][j] = __builtin_amdgcn_mfma_f32_16x16x32_bf16(ahR[i], blI, aI[i][j], 0,0,0);
        aI[i][j] = __builtin_amdgcn_mfma_f32_16x16x32_bf16(alR[i], bhI, aI[i][j], 0,0,0);
        aI[i][j] = __builtin_amdgcn_mfma_f32_16x16x32_bf16(ahI[i], bhR, aI[i][j], 0,0,0);
        aI[i][j] = __builtin_amdgcn_mfma_f32_16x16x32_bf16(ahI[i], blR, aI[i][j], 0,0,0);
        aI[i][j] = __builtin_amdgcn_mfma_f32_16x16x32_bf16(alI[i], bhR, aI[i][j], 0,0,0);
      }
    }
  }
  // epilogue: twiddle and write U (split) in place over T rows this wave read — coalesced in r
  #pragma unroll
  for (int i=0;i<2;i++){
    int f0b = mh*64 + wr1 + i*16 + lk*4;
    #pragma unroll
    for (int j=0;j<4;j++){
      int r = wc1 + j*16 + lr;
      #pragma unroll
      for (int e=0;e<4;e++){
        float2 t = tw2[(f0b+e)*128 + r];
        float rr = aR[i][j][e], ii = aI[i][j][e];
        float ur = rr*t.x - ii*t.y, ui = rr*t.y + ii*t.x;
        size_t o = (size_t)(f0b+e)*32768 + (size_t)row*128 + r;
        wr_split(TRH, TRL, o, ur);
        wr_split(TIH, TIL, o, ui);
      }
    }
  }
}

// ---------------- FFT stage 3 (MFMA): stages from U split planes, writes Hn packed bf16 hi/lo ----------------
__global__ __launch_bounds__(256) void fft3_mfma_k(const float* __restrict__ ws, float* __restrict__ R0,
                                                   size_t rstride){
  float* Rb = R0 + (size_t)blockIdx.y*rstride;
  const unsigned short* URH = (const unsigned short*)(Rb + R_SCR);
  const unsigned short* URL = URH + 4194304;
  const unsigned short* UIH = URL + 4194304;
  const unsigned short* UIL = UIH + 4194304;
  unsigned short* HHo = (unsigned short*)(Rb + R_SCR + HNOFF);
  unsigned short* HLo = (unsigned short*)(Rb + R_SCR + HNOFF + 2097152);
  const unsigned int* PK = (const unsigned int*)(ws + OFF_PACK);
  __shared__ unsigned int BRh[128][20], BRl[128][20], BIh[128][20], BIl[128][20];
  int tid = threadIdx.x;
  int lane = tid & 63, wid = tid >> 6;
  int wr = (wid>>1)*64, wc = (wid&1)*64;
  int lr = lane & 15, lk = lane >> 4;
  int brow = blockIdx.x;                // d row 0..255
  f32x4 ac[4][4] = {};
  int bc = tid & 127, grp = tid >> 7;
  for (int kt = 0; kt < 4; kt++){
    #pragma unroll
    for (int p=0;p<8;p++){
      int kp = grp*8 + p;
      int k = kt*32 + 2*kp;            // f0
      size_t o0 = (size_t)k*32768 + (size_t)brow*128 + bc;
      BRh[bc][kp] = (unsigned)URH[o0] | ((unsigned)URH[o0+32768] << 16);
      BRl[bc][kp] = (unsigned)URL[o0] | ((unsigned)URL[o0+32768] << 16);
      BIh[bc][kp] = (unsigned)UIH[o0] | ((unsigned)UIH[o0+32768] << 16);
      BIl[bc][kp] = (unsigned)UIL[o0] | ((unsigned)UIL[o0+32768] << 16);
    }
    __syncthreads();
    short8 ahR[4], alR[4], ahI[4], alI[4];
    #pragma unroll
    for (int i=0;i<4;i++){
      int off = (wr + i*16 + lr)*64 + kt*16 + lk*4;
      ahR[i] = ld8g(PK + ETA_RH + off); alR[i] = ld8g(PK + ETA_RL + off);
      ahI[i] = ld8g(PK + ETA_IH + off); alI[i] = ld8g(PK + ETA_IL + off);
    }
    #pragma unroll
    for (int j=0;j<4;j++){
      int col = wc + j*16 + lr;
      short8 bhR = *(const short8*)&BRh[col][lk*4];
      short8 blR = *(const short8*)&BRl[col][lk*4];
      short8 bhI = *(const short8*)&BIh[col][lk*4];
      short8 blI = *(const short8*)&BIl[col][lk*4];
      #pragma unroll
      for (int i=0;i<4;i++){
        ac[i][j] = __builtin_amdgcn_mfma_f32_16x16x32_bf16(ahR[i], bhI, ac[i][j], 0,0,0);
        ac[i][j] = __builtin_amdgcn_mfma_f32_16x16x32_bf16(ahR[i], blI, ac[i][j], 0,0,0);
        ac[i][j] = __builtin_amdgcn_mfma_f32_16x16x32_bf16(alR[i], bhI, ac[i][j], 0,0,0);
        ac[i][j] = __builtin_amdgcn_mfma_f32_16x16x32_bf16(ahI[i], bhR, ac[i][j], 0,0,0);
        ac[i][j] = __builtin_amdgcn_mfma_f32_16x16x32_bf16(ahI[i], blR, ac[i][j], 0,0,0);
        ac[i][j] = __builtin_amdgcn_mfma_f32_16x16x32_bf16(alI[i], bhR, ac[i][j], 0,0,0);
      }
    }
    __syncthreads();
  }
  #pragma unroll
  for (int i=0;i<4;i++)
    #pragma unroll
    for (int e=0;e<4;e++){
      int m = wr + i*16 + lk*4 + e;     // u
      #pragma unroll
      for (int j=0;j<4;j++){
        int col = wc + j*16 + lr;       // r
        float v = ac[i][j][e];
        unsigned u = __float_as_uint(v);
        size_t o = (size_t)brow*HWSZ + m*128 + col;
        HHo[o] = (unsigned short)(u >> 16);
        HLo[o] = b16rn(v - __uint_as_float(u & 0xFFFF0000u));
      }
    }
}

// ---------------- P & Ri via LDS-free MFMA over packed planes ----------------
__global__ __launch_bounds__(256) void pri3_k(float* __restrict__ R0, size_t rstride){
  float* Rb = R0 + (size_t)blockIdx.z*rstride;
  int sp = blockIdx.x, head = blockIdx.y;
  const unsigned short* QH = (const unsigned short*)(Rb + R_QKV);
  const unsigned short* QL = (const unsigned short*)(Rb + R_QKV + 2097152);
  const unsigned short* KH = (const unsigned short*)(Rb + R_H);
  const unsigned short* KL = (const unsigned short*)(Rb + R_H + 2097152);
  const unsigned short* HNH = (const unsigned short*)(Rb + R_SCR + HNOFF);
  const unsigned short* HNL = HNH + 2097152*2;
  float* Pp = Rb + R_PP;
  float* Rp = Rb + R_RP;
  int tid = threadIdx.x, lane = tid & 63, wid = tid >> 6;
  int wr = (wid>>1)*32, wc = (wid&1)*32;
  int lr = lane & 15, lk = lane >> 4;
  size_t qoff[2], koff[2];
  #pragma unroll
  for (int i=0;i<2;i++) qoff[i] = (size_t)(head*64 + wr + i*16 + lr)*HWSZ + sp*256 + lk*8;
  #pragma unroll
  for (int j=0;j<2;j++) koff[j] = (size_t)(head*64 + wc + j*16 + lr)*HWSZ + sp*256 + lk*8;
  f32x4 aP[2][2] = {}, aRi[2][2] = {};
  short8 qh[2][2], ql[2][2], k1h[2][2], k1l[2][2], k2h[2][2], k2l[2][2];
#define LDPRI(B,T) { int d = (T)*32; \
    _Pragma("unroll") \
    for (int i=0;i<2;i++){ \
      qh[B][i] = ld8s(QH + qoff[i] + d); \
      ql[B][i] = ld8s(QL + qoff[i] + d); } \
    _Pragma("unroll") \
    for (int j=0;j<2;j++){ \
      k1h[B][j] = ld8s(KH + koff[j] + d); \
      k1l[B][j] = ld8s(KL + koff[j] + d); \
      k2h[B][j] = ld8s(HNH + koff[j] + d); \
      k2l[B][j] = ld8s(HNL + koff[j] + d); } }
  LDPRI(0,0);
  #pragma unroll
  for (int kt = 0; kt < 8; kt++){
    int cur = kt & 1;
    if (kt < 7) LDPRI(cur^1, kt+1);
    #pragma unroll
    for (int i=0;i<2;i++)
      #pragma unroll
      for (int j=0;j<2;j++){
        aP[i][j]  = __builtin_amdgcn_mfma_f32_16x16x32_bf16(qh[cur][i], k1h[cur][j], aP[i][j], 0,0,0);
        aP[i][j]  = __builtin_amdgcn_mfma_f32_16x16x32_bf16(qh[cur][i], k1l[cur][j], aP[i][j], 0,0,0);
        aP[i][j]  = __builtin_amdgcn_mfma_f32_16x16x32_bf16(ql[cur][i], k1h[cur][j], aP[i][j], 0,0,0);
        aRi[i][j] = __builtin_amdgcn_mfma_f32_16x16x32_bf16(qh[cur][i], k2h[cur][j], aRi[i][j], 0,0,0);
        aRi[i][j] = __builtin_amdgcn_mfma_f32_16x16x32_bf16(qh[cur][i], k2l[cur][j], aRi[i][j], 0,0,0);
        aRi[i][j] = __builtin_amdgcn_mfma_f32_16x16x32_bf16(ql[cur][i], k2h[cur][j], aRi[i][j], 0,0,0);
      }
  }
#undef LDPRI
  size_t obase = ((size_t)(sp*4 + head)) << 12;
  #pragma unroll
  for (int i=0;i<2;i++)
    #pragma unroll
    for (int e=0;e<4;e++){
      int row = wr + i*16 + lk*4 + e;
      #pragma unroll
      for (int j=0;j<2;j++){
        int col = wc + j*16 + lr;
        size_t o = obase + (size_t)row*64 + col;
        Pp[o] = aP[i][j][e];
        Rp[o] = aRi[i][j][e];
      }
    }
}

// ---------------- split reduce + dw stat fold ----------------
__global__ __launch_bounds__(256) void red_k(float* __restrict__ R0, size_t rstride){
  float* Rb = R0 + (size_t)blockIdx.y*rstride;
  const float* Pp = Rb + R_PP;
  const float* Rp = Rb + R_RP;
  float* Ps = Rb + R_PS;
  float* Rs = Rb + R_RS;
  int tid = threadIdx.x;
  #pragma unroll
  for (int rep=0; rep<2; rep++){
    int g = blockIdx.x*512 + rep*256 + tid;
    int head = g >> 12, loc = g & 4095;
    float p = 0.f, ri = 0.f;
    for (int sp=0; sp<64; sp++){
      size_t o = ((size_t)(sp*4+head)<<12) + loc;
      p += Pp[o]; ri += Rp[o];
    }
    Ps[g] = p; Rs[g] = ri;
  }
  if (blockIdx.x == 0){
    const float* part = Rb + R_DWP;
    for (int ch = tid; ch < CH3; ch += 256){
      float s=0.f, sa=0.f, sq=0.f;
      #pragma unroll
      for (int sl=0; sl<4; sl++){
        s  += part[ch*4+sl];
        sa += part[3072+ch*4+sl];
        sq += part[6144+ch*4+sl];
      }
      Rb[R_SSUM+ch]=s; Rb[R_SALT+ch]=sa; Rb[R_SSQ+ch]=sq;
    }
  }
}

// ---------------- attn build ----------------
__global__ __launch_bounds__(256) void attn_build_k(const float* __restrict__ ws, float* __restrict__ R0,
                                                    size_t rstride, const float* __restrict__ temperature){
  float* Rb = R0 + (size_t)blockIdx.y*rstride;
  const float* Ps   = Rb + R_PS;
  const float* Rs   = Rb + R_RS;
  const float* ssum = Rb + R_SSUM;
  const float* salt = Rb + R_SALT;
  const float* ssq  = Rb + R_SSQ;
  float* attn = Rb + R_ATTN;
  const float* hmg  = ws + OFF_HM;
  __shared__ float Rn[64][65], Ril[64][65], hm[64];
  int head = blockIdx.x;
  int tid = threadIdx.x;
  if (tid < 64) hm[tid] = hmg[tid];
  for (int t=0;t<16;t++){
    int idx = tid + t*256; int c = idx>>6, d = idx&63;
    float P = Ps[head*4096 + idx], Ri = Rs[head*4096 + idx];
    int qch = head*64 + c;
    int kch = 256 + head*64 + d;
    float qs=ssum[qch], qa=salt[qch], qn=fmaxf(sqrtf(ssq[qch]), 1e-12f);
    float ks=ssum[kch], ka=salt[kch], kn=fmaxf(sqrtf(ssq[kch]), 1e-12f);
    float Rr = 0.5f*(16384.0f*P + qs*ks + qa*ka);
    float sc = 1.0f/(qn*kn);
    Rn[c][d]  = Rr*sc;
    Ril[c][d] = Ri*sc;
  }
  __syncthreads();
  float tmp2 = temperature[(head+2)&3];
  for (int t=0;t<16;t++){
    int idx = tid + t*256; int c = idx>>6, e = idx&63;
    float s = Rn[c][e];
    #pragma unroll 8
    for (int d=0; d<64; d++) s += Ril[c][d]*hm[(e-d)&63];
    attn[((size_t)head<<12) + (size_t)(c*64+e)] = s*tmp2;
  }
}

// ---------------- nested top-k masked softmax ----------------
__global__ __launch_bounds__(64) void topk_k(float* __restrict__ R0, size_t rstride,
                                             const float* __restrict__ attn_w){
  float* Rb = R0 + (size_t)blockIdx.y*rstride;
  const float* attn = Rb + R_ATTN;
  float* Acomb = Rb + R_ACOMB;
  int blk = blockIdx.x;
  int tid = threadIdx.x;
  __shared__ float row[64];
  float v = attn[(size_t)blk*64 + tid];
  row[tid] = v;
  __syncthreads();
  int rank = 0; float vmax = -1e30f;
  for (int l=0;l<64;l++){
    float w = row[l];
    if (w > v || (w == v && l < tid)) rank++;
    vmax = fmaxf(vmax, w);
  }
  float e = expf(v - vmax);
  const int kks[4] = {32,42,48,51};
  float denom[4];
  #pragma unroll
  for (int i=0;i<4;i++){
    float x = (rank < kks[i]) ? e : 0.0f;
    #pragma unroll
    for (int off=32; off; off>>=1) x += __shfl_xor(x, off);
    denom[i] = x;
  }
  float wgt = 0.f;
  #pragma unroll
  for (int i=0;i<4;i++) if (rank < kks[i]) wgt += attn_w[i] / denom[i];
  Acomb[(size_t)blk*64 + tid] = e * wgt;
}

// ---------------- out_head = A_comb @ v, packed output ----------------
__global__ __launch_bounds__(256) void av_k(float* __restrict__ R0, size_t rstride){
  float* Rb = R0 + (size_t)blockIdx.z*rstride;
  const float* Acomb = Rb + R_ACOMB;
  unsigned int* BqH = (unsigned int*)(Rb + R_H);
  unsigned int* BqL = BqH + 2097152;
  int head = blockIdx.y;
  int n0 = blockIdx.x*64;
  const float* Vb = Rb + R_QKV + (size_t)(512 + head*64)*HWSZ;
  __shared__ float As[64][65], Bs[16][65];
  int tid=threadIdx.x, tx=tid&15, ty=tid>>4;
  for (int t=0;t<16;t++){ int idx=tid+t*256; As[idx>>6][idx&63] = Acomb[((size_t)head<<12)+idx]; }
  __syncthreads();
  float acc[4][4]={};
  for (int k0=0;k0<64;k0+=16){
    #pragma unroll
    for (int i=0;i<4;i++){ int id=tid+i*256; int nn=id&63, k=id>>6;
      Bs[k][nn] = Vb[(size_t)(k0+k)*HWSZ + n0+nn]; }
    __syncthreads();
    #pragma unroll
    for (int k=0;k<16;k++){
      float a[4], bv[4];
      #pragma unroll
      for (int i=0;i<4;i++) a[i]=As[ty*4+i][k0+k];
      #pragma unroll
      for (int j=0;j<4;j++) bv[j]=Bs[k][tx*4+j];
      #pragma unroll
      for (int i=0;i<4;i++)
        #pragma unroll
        for (int j=0;j<4;j++) acc[i][j] += a[i]*bv[j];
    }
    __syncthreads();
  }
  int kpa = head*32 + ty*2;
  int kba = kpa >> 2, qa = kpa & 3;
  int kpb = kpa + 1;
  int kbb = kpb >> 2, qb = kpb & 3;
  #pragma unroll
  for (int j=0;j<4;j++){
    int n = n0 + tx*4 + j;
    BqH[((size_t)kba*HWSZ + n)*4 + qa] = pk_hi(acc[0][j], acc[1][j]);
    BqL[((size_t)kba*HWSZ + n)*4 + qa] = pk_lo(acc[0][j], acc[1][j]);
    BqH[((size_t)kbb*HWSZ + n)*4 + qb] = pk_hi(acc[2][j], acc[3][j]);
    BqL[((size_t)kbb*HWSZ + n)*4 + qb] = pk_lo(acc[2][j], acc[3][j]);
  }
}

extern "C" void kernel_launch(void* const* d_in, const int* in_sizes, int n_in,
                              void* d_out, int out_size, void* d_ws, size_t ws_size,
                              hipStream_t stream) {
  const float* x     = (const float*)d_in[0];
  const float* gn_w  = (const float*)d_in[1];
  const float* gn_b  = (const float*)d_in[2];
  const float* w_qkv = (const float*)d_in[3];
  const float* w_dw  = (const float*)d_in[4];
  const float* w_out = (const float*)d_in[5];
  const float* b_out = (const float*)d_in[6];
  const float* temperature = (const float*)d_in[7];
  const float* attn_w = (const float*)d_in[8];
  float* out = (float*)d_out;
  float* ws  = (float*)d_ws;
  unsigned int* AW = (unsigned int*)(ws + OFF_AW);
  float* R0 = ws + SHARED_END;
  const size_t CHW = (size_t)NC*HWSZ;

  size_t need2 = (SHARED_END + 2*RSTRIDE)*sizeof(float);
  size_t need4 = (SHARED_END + 4*RSTRIDE)*sizeof(float);
  int zb = (ws_size >= need4) ? 4 : (ws_size >= need2) ? 2 : 1;

  init_tables_k<<<64,256,0,stream>>>(ws);
  wpack_k<<<512,256,0,stream>>>(w_qkv, w_out, AW);
  gn_part_k<<<1024,256,0,stream>>>(x, (float2*)(ws+OFF_GNP));
  gn_fin_k<<<1,128,0,stream>>>((const float2*)(ws+OFF_GNP), gn_w, gn_b,
                               ws+OFF_SCALE, ws+OFF_SHIFT);

  for (int b0 = 0; b0 < 4; b0 += zb){
    packx_k<<<dim3(64,32,zb),256,0,stream>>>(x + (size_t)b0*CHW, ws+OFF_SCALE+b0*NC,
                                             ws+OFF_SHIFT+b0*NC, R0, RSTRIDE);
    gemm_pk<<<dim3(128,6,zb),256,0,stream>>>(AW+AWQ_H, AW+AWQ_L,
                                             (unsigned int*)(R0+R_H), (unsigned int*)(R0+R_H)+2097152,
                                             nullptr, R0+R_SCR, RSTRIDE, RSTRIDE);
    dwconv_tiled_k<<<dim3(3072,zb),256,0,stream>>>(R0, RSTRIDE, w_dw);
    fft1_mfma_k<<<dim3(256,zb),256,0,stream>>>(ws, R0, RSTRIDE);
    fft2_mfma_k<<<dim3(512,zb),256,0,stream>>>(ws, R0, RSTRIDE);
    fft3_mfma_k<<<dim3(256,zb),256,0,stream>>>(ws, R0, RSTRIDE);
    pri3_k<<<dim3(64,4,zb),256,0,stream>>>(R0, RSTRIDE);
    red_k<<<dim3(32,zb),256,0,stream>>>(R0, RSTRIDE);
    attn_build_k<<<dim3(4,zb),256,0,stream>>>(ws, R0, RSTRIDE, temperature);
    topk_k<<<dim3(256,zb),64,0,stream>>>(R0, RSTRIDE, attn_w);
    av_k<<<dim3(256,4,zb),256,0,stream>>>(R0, RSTRIDE);
    gemm_pk<<<dim3(128,2,zb),256,0,stream>>>(AW+AWO_H, AW+AWO_L,
                                             (unsigned int*)(R0+R_H), (unsigned int*)(R0+R_H)+2097152,
                                             b_out, out + (size_t)b0*CHW, RSTRIDE, CHW);
  }
}

// Round 15
// 807.954 us; speedup vs baseline: 1.1216x; 1.1216x over previous
//
#include <hip/hip_runtime.h>
#include <math.h>

#define NC 256
#define CH3 768
#define HWSZ 16384

typedef __attribute__((ext_vector_type(8))) short short8;
typedef __attribute__((ext_vector_type(4))) float f32x4;
typedef __attribute__((ext_vector_type(4))) unsigned int u32x4;

// ---- shared (table) region ----
static const size_t OFF_TW1   = 0;
static const size_t OFF_TW2   = 32768;
static const size_t OFF_HM    = 65536;
static const size_t OFF_SCALE = 65600;
static const size_t OFF_SHIFT = 66624;
static const size_t OFF_PACK  = 67648;
static const size_t OFF_AW    = 182336;
static const size_t OFF_GNP   = 444480;
static const size_t SHARED_END= 446528;

// ---- per-batch region ----
// R_QKV: [0..2.1M) QfH u16, [2.1M..4.19M) QfL u16, [4.19M..8.39M) dead, [8.39M..12.58M) V fp32
// R_SCR: pre-dw qkv fp32 -> T/U complex fp32 in-place [0..8.39M) ; Hn hi/lo planes at HNOFF
// R_H  : Bq packed (gemm in) -> Kn hi/lo u16 planes -> Bq2 packed (av out)
static const size_t R_QKV  = 0;
static const size_t R_SCR  = 12582912;
static const size_t R_H    = 25165824;
static const size_t R_PP   = 29360128;
static const size_t R_RP   = 30408704;
static const size_t R_ATTN = 31457280;
static const size_t R_ACOMB= 31473664;
static const size_t R_PS   = 31490048;
static const size_t R_RS   = 31506432;
static const size_t R_DWP  = 31522816;
static const size_t R_SSUM = 31532032;
static const size_t R_SALT = 31532800;
static const size_t R_SSQ  = 31533568;
static const size_t RSTRIDE= 31534336;
static const size_t HNOFF  = 8388608;       // floats into R_SCR

#define TDA_RH 0
#define TDA_RL 8192
#define TDA_IH 16384
#define TDA_IL 24576
#define ETA_RH 32768
#define ETA_RL 40960
#define ETA_IH 49152
#define ETA_IL 57344
#define STB_RH 65536
#define STB_RL 73728
#define STB_IH 81920
#define STB_IL 90112
#define STB_NIH 98304
#define STB_NIL 106496

#define AWQ_H 0
#define AWQ_L 98304
#define AWO_H 196608
#define AWO_L 229376

__device__ inline unsigned short b16rn(float x){
  unsigned u = __float_as_uint(x);
  return (unsigned short)((u + 0x7FFFu + ((u>>16)&1u)) >> 16);
}
__device__ inline unsigned int pk_hi(float x, float y){
  return (__float_as_uint(x)>>16) | (__float_as_uint(y) & 0xFFFF0000u);
}
__device__ inline unsigned int pk_lo(float x, float y){
  float xl = x - __uint_as_float(__float_as_uint(x) & 0xFFFF0000u);
  float yl = y - __uint_as_float(__float_as_uint(y) & 0xFFFF0000u);
  return (unsigned)b16rn(xl) | ((unsigned)b16rn(yl)<<16);
}
__device__ inline short8 ld8g(const unsigned int* p){ return *(const short8*)p; }
__device__ inline short8 ld8s(const unsigned short* p){ return *(const short8*)p; }
__device__ inline void wr_split(unsigned short* H, unsigned short* L, size_t o, float v){
  unsigned u = __float_as_uint(v);
  H[o] = (unsigned short)(u >> 16);
  L[o] = b16rn(v - __uint_as_float(u & 0xFFFF0000u));
}

// ---------------- tables ----------------
__global__ __launch_bounds__(256) void init_tables_k(float* __restrict__ ws){
  int idx = blockIdx.x*256 + threadIdx.x;
  float2* tw1 = (float2*)(ws + OFF_TW1);
  float2* tw2 = (float2*)(ws + OFF_TW2);
  unsigned int* pk = (unsigned int*)(ws + OFF_PACK);
  const double P2 = 6.283185307179586476925286766559005;
  int m = idx >> 7, k = idx & 127;
  double a2 = P2 * (double)(m*k) / 16384.0;
  tw1[idx] = make_float2((float)cos(a2), (float)(-sin(a2)));
  tw2[idx] = make_float2((float)cos(a2), (float)( sin(a2)));
  if (idx < 64){
    double acc = 0.0;
    for (int v = 1; v < 32; v++) acc += sin(P2 * (double)((v*idx) & 63) / 64.0);
    ws[OFF_HM + idx] = (float)(-acc / 32.0);
  }
  if (idx < 8192){
    int r = idx >> 6, kp = idx & 63;
    int k0 = 2*kp, k1 = 2*kp+1;
    double a0 = P2 * (double)((r*k0) & 127) / 128.0;
    double a1 = P2 * (double)((r*k1) & 127) / 128.0;
    float c0 = (float)cos(a0), c1 = (float)cos(a1);
    float s0 = (float)sin(a0), s1 = (float)sin(a1);
    pk[TDA_RH + idx] = pk_hi(c0, c1);  pk[TDA_RL + idx] = pk_lo(c0, c1);
    pk[TDA_IH + idx] = pk_hi(-s0,-s1); pk[TDA_IL + idx] = pk_lo(-s0,-s1);
    pk[ETA_RH + idx] = pk_hi(c0, c1);  pk[ETA_RL + idx] = pk_lo(c0, c1);
    pk[ETA_IH + idx] = pk_hi(s0, s1);  pk[ETA_IL + idx] = pk_lo(s0, s1);
    float sr0, si0, sr1, si1;
    {
      int d0 = (r - k0) & 127, d1 = (r - k1) & 127;
      if (d0 == 0){ sr0 = 64.f; si0 = 0.f; }
      else if ((d0 & 1) == 0){ sr0 = 0.f; si0 = 0.f; }
      else { double th = 3.1415926535897932384626 * (double)d0 / 128.0;
             sr0 = 1.f; si0 = (float)(cos(th)/sin(th)); }
      if (d1 == 0){ sr1 = 64.f; si1 = 0.f; }
      else if ((d1 & 1) == 0){ sr1 = 0.f; si1 = 0.f; }
      else { double th = 3.1415926535897932384626 * (double)d1 / 128.0;
             sr1 = 1.f; si1 = (float)(cos(th)/sin(th)); }
    }
    pk[STB_RH + idx]  = pk_hi(sr0, sr1);  pk[STB_RL + idx]  = pk_lo(sr0, sr1);
    pk[STB_IH + idx]  = pk_hi(si0, si1);  pk[STB_IL + idx]  = pk_lo(si0, si1);
    pk[STB_NIH + idx] = pk_hi(-si0,-si1); pk[STB_NIL + idx] = pk_lo(-si0,-si1);
  }
}

// ---------------- pack weights (once) ----------------
__global__ __launch_bounds__(256) void wpack_k(const float* __restrict__ wqkv, const float* __restrict__ wout,
                                               unsigned int* __restrict__ aw){
  int id = blockIdx.x*256 + threadIdx.x;
  int row = id >> 7, kp = id & 127;
  if (row < CH3){
    float v0 = wqkv[row*256 + 2*kp], v1 = wqkv[row*256 + 2*kp + 1];
    aw[AWQ_H + row*128 + kp] = pk_hi(v0, v1);
    aw[AWQ_L + row*128 + kp] = pk_lo(v0, v1);
  } else {
    int r2 = row - CH3;
    float v0 = wout[r2*256 + 2*kp], v1 = wout[r2*256 + 2*kp + 1];
    aw[AWO_H + r2*128 + kp] = pk_hi(v0, v1);
    aw[AWO_L + r2*128 + kp] = pk_lo(v0, v1);
  }
}

// ---------------- groupnorm stats ----------------
__global__ __launch_bounds__(256) void gn_part_k(const float* __restrict__ x, float2* __restrict__ part){
  int id = blockIdx.x;
  const float4* p = (const float4*)(x + (size_t)id*HWSZ);
  int tid = threadIdx.x;
  float s = 0.f, sq = 0.f;
  #pragma unroll
  for (int i = 0; i < 16; i++){
    float4 v = p[tid + i*256];
    s  += v.x+v.y+v.z+v.w;
    sq += v.x*v.x+v.y*v.y+v.z*v.z+v.w*v.w;
  }
  __shared__ float r1[256], r2[256];
  r1[tid]=s; r2[tid]=sq; __syncthreads();
  for (int off=128; off; off>>=1){
    if (tid<off){ r1[tid]+=r1[tid+off]; r2[tid]+=r2[tid+off]; }
    __syncthreads();
  }
  if (tid==0) part[id] = make_float2(r1[0], r2[0]);
}
__global__ __launch_bounds__(128) void gn_fin_k(const float2* __restrict__ part, const float* __restrict__ gw,
                                                const float* __restrict__ gb, float* __restrict__ scale,
                                                float* __restrict__ shift){
  int bg = threadIdx.x;
  int b = bg >> 5, g = bg & 31;
  float s = 0.f, sq = 0.f;
  #pragma unroll
  for (int i = 0; i < 8; i++){
    float2 v = part[b*NC + g*8 + i];
    s += v.x; sq += v.y;
  }
  const float n = 8.0f*HWSZ;
  float mu = s/n, var = sq/n - mu*mu;
  float rs = rsqrtf(var + 1e-5f);
  for (int i = 0; i < 8; i++){
    int ch = g*8 + i;
    float sc = rs * gw[ch];
    scale[b*NC + ch] = sc;
    shift[b*NC + ch] = gb[ch] - mu*sc;
  }
}

// ---------------- pack GN(x) into Bq planes ----------------
__global__ __launch_bounds__(256) void packx_k(const float* __restrict__ xbase, const float* __restrict__ scale,
                                               const float* __restrict__ shift, float* __restrict__ R0,
                                               size_t rstride){
  int bz = blockIdx.z;
  const float* xb = xbase + (size_t)bz*NC*HWSZ;
  const float* sc = scale + bz*NC;
  const float* sh = shift + bz*NC;
  unsigned int* BqH = (unsigned int*)(R0 + (size_t)bz*rstride + R_H);
  unsigned int* BqL = BqH + 2097152;
  int kb = blockIdx.y;
  int n = blockIdx.x*256 + threadIdx.x;
  float v[8];
  #pragma unroll
  for (int c = 0; c < 8; c++){
    int ch = kb*8 + c;
    v[c] = xb[(size_t)ch*HWSZ + n]*sc[ch] + sh[ch];
  }
  u32x4 h, l;
  #pragma unroll
  for (int q = 0; q < 4; q++){
    h[q] = pk_hi(v[2*q], v[2*q+1]);
    l[q] = pk_lo(v[2*q], v[2*q+1]);
  }
  *(u32x4*)&BqH[((size_t)kb*HWSZ + n)*4] = h;
  *(u32x4*)&BqL[((size_t)kb*HWSZ + n)*4] = l;
}

// ---------------- LDS-free packed split-bf16 MFMA GEMM, depth-1 register pipeline ----------------
__global__ __launch_bounds__(256) void gemm_pk(const unsigned int* __restrict__ Ah, const unsigned int* __restrict__ Al,
                                               const unsigned int* __restrict__ Bh0, const unsigned int* __restrict__ Bl0,
                                               const float* __restrict__ bias, float* __restrict__ C0,
                                               size_t bstride, size_t cstride){
  const unsigned int* Bh = Bh0 + (size_t)blockIdx.z*bstride;
  const unsigned int* Bl = Bl0 + (size_t)blockIdx.z*bstride;
  float* C = C0 + (size_t)blockIdx.z*cstride;
  int tid = threadIdx.x;
  int lane = tid & 63, wid = tid >> 6;
  int m0 = blockIdx.y*128, n0 = blockIdx.x*128;
  int wr = (wid>>1)*64, wc = (wid&1)*64;
  int lr = lane & 15, lk = lane >> 4;
  f32x4 acc[4][4] = {};
  size_t aoff[4], boff[4];
  #pragma unroll
  for (int i=0;i<4;i++) aoff[i] = (size_t)(m0 + wr + i*16 + lr)*128 + lk*4;
  #pragma unroll
  for (int j=0;j<4;j++) boff[j] = ((size_t)lk*HWSZ + n0 + wc + j*16 + lr)*4;
  short8 aH[2][4], aL[2][4], bH[2][4], bL[2][4];
  #pragma unroll
  for (int i=0;i<4;i++){ aH[0][i] = ld8g(Ah + aoff[i]); aL[0][i] = ld8g(Al + aoff[i]); }
  #pragma unroll
  for (int j=0;j<4;j++){ bH[0][j] = ld8g(Bh + boff[j]); bL[0][j] = ld8g(Bl + boff[j]); }
  #pragma unroll
  for (int kt = 0; kt < 8; kt++){
    int cur = kt & 1, nxt = cur ^ 1;
    if (kt < 7){
      size_t da = (size_t)(kt+1)*16;
      size_t db = (size_t)(kt+1)*4*HWSZ*4;
      #pragma unroll
      for (int i=0;i<4;i++){ aH[nxt][i] = ld8g(Ah + aoff[i] + da); aL[nxt][i] = ld8g(Al + aoff[i] + da); }
      #pragma unroll
      for (int j=0;j<4;j++){ bH[nxt][j] = ld8g(Bh + boff[j] + db); bL[nxt][j] = ld8g(Bl + boff[j] + db); }
    }
    #pragma unroll
    for (int i=0;i<4;i++)
      #pragma unroll
      for (int j=0;j<4;j++){
        acc[i][j] = __builtin_amdgcn_mfma_f32_16x16x32_bf16(aH[cur][i], bH[cur][j], acc[i][j], 0,0,0);
        acc[i][j] = __builtin_amdgcn_mfma_f32_16x16x32_bf16(aH[cur][i], bL[cur][j], acc[i][j], 0,0,0);
        acc[i][j] = __builtin_amdgcn_mfma_f32_16x16x32_bf16(aL[cur][i], bH[cur][j], acc[i][j], 0,0,0);
      }
  }
  #pragma unroll
  for (int i=0;i<4;i++){
    #pragma unroll
    for (int e=0;e<4;e++){
      int row = m0 + wr + i*16 + lk*4 + e;
      float bb = bias ? bias[row] : 0.0f;
      #pragma unroll
      for (int j=0;j<4;j++)
        C[(size_t)row*HWSZ + n0 + wc + j*16 + lr] = acc[i][j][e] + bb;
    }
  }
}

// ---------------- depthwise 3x3, tiled; epilogue packs Qf (flipped) / Kn planes / V fp32 ----------------
__global__ __launch_bounds__(256) void dwconv_tiled_k(float* __restrict__ R0, size_t rstride,
                                                      const float* __restrict__ wdw){
  float* Rb = R0 + (size_t)blockIdx.y*rstride;
  int blk = blockIdx.x;
  int ch = blk >> 2, sl = blk & 3;
  int h0 = sl*32;
  const float* in = Rb + R_SCR + (size_t)ch*HWSZ;
  float* part = Rb + R_DWP;
  float w[9];
  #pragma unroll
  for (int i=0;i<9;i++) w[i] = wdw[ch*9+i];
  __shared__ float tile[34][132];
  __shared__ float r0[256], r1[256], r2[256];
  int tid = threadIdx.x;
  #pragma unroll
  for (int i = 0; i < 5; i++){
    int id = tid + i*256;
    if (id < 1088){
      int r = id >> 5, c4 = id & 31;
      int gh = h0 - 1 + r;
      float4 v = (gh >= 0 && gh < 128) ? *(const float4*)&in[gh*128 + c4*4]
                                       : make_float4(0.f,0.f,0.f,0.f);
      *(float4*)&tile[r][c4*4] = v;
    }
  }
  __syncthreads();
  float s=0.f, sa=0.f, sq=0.f;
  #pragma unroll
  for (int it=0; it<4; it++){
    int idx = it*256 + tid;
    int lh = idx >> 5;
    int xq = idx & 31;
    int xb4 = xq*4;
    float o[4];
    #pragma unroll
    for (int e=0;e<4;e++){
      int xw = xb4 + e;
      float acc = 0.f;
      #pragma unroll
      for (int ky=0; ky<3; ky++){
        const float* tr = &tile[lh+ky][xw];
        if (xw > 0)   acc += tr[-1]*w[ky*3+0];
                      acc += tr[ 0]*w[ky*3+1];
        if (xw < 127) acc += tr[ 1]*w[ky*3+2];
      }
      o[e] = acc;
      s += acc; sq += acc*acc;
      sa += (e & 1) ? -acc : acc;
    }
    int sbase = (h0+lh)*128 + xb4;
    if (ch < 256){
      // Q channel: packed bf16 hi/lo at FLIPPED positions (scalar — reversed order)
      unsigned short* QHo = (unsigned short*)(Rb + R_QKV);
      unsigned short* QLo = (unsigned short*)(Rb + R_QKV + 2097152);
      size_t ro = (size_t)ch*HWSZ;
      #pragma unroll
      for (int e=0;e<4;e++){
        int sf = (16384 - (sbase+e)) & 16383;
        wr_split(QHo, QLo, ro + sf, o[e]);
      }
    } else if (ch < 512){
      // K channel: packed Kn planes, single 8B store per plane (bit-identical to wr_split x4)
      unsigned short* KHo = (unsigned short*)(Rb + R_H);
      unsigned short* KLo = (unsigned short*)(Rb + R_H + 2097152);
      size_t ro = (size_t)(ch-256)*HWSZ;
      unsigned long long ph = 0ull, pl = 0ull;
      #pragma unroll
      for (int e=0;e<4;e++){
        unsigned u = __float_as_uint(o[e]);
        ph |= (unsigned long long)(unsigned short)(u >> 16) << (16*e);
        pl |= (unsigned long long)b16rn(o[e] - __uint_as_float(u & 0xFFFF0000u)) << (16*e);
      }
      *(unsigned long long*)&KHo[ro + sbase] = ph;
      *(unsigned long long*)&KLo[ro + sbase] = pl;
    } else {
      // V channel: fp32 only
      *(float4*)&(Rb + R_QKV + (size_t)ch*HWSZ)[sbase] = make_float4(o[0],o[1],o[2],o[3]);
    }
  }
  r0[tid]=s; r1[tid]=sa; r2[tid]=sq; __syncthreads();
  for (int off=128; off; off>>=1){
    if (tid<off){ r0[tid]+=r0[tid+off]; r1[tid]+=r1[tid+off]; r2[tid]+=r2[tid+off]; }
    __syncthreads();
  }
  if (tid==0){ part[blk]=r0[0]; part[3072+blk]=r1[0]; part[6144+blk]=r2[0]; }
}

// ---------------- FFT stage 1 (MFMA): reads Kn planes, writes T fp32 [f0][row][b2] ----------------
__global__ __launch_bounds__(256) void fft1_mfma_k(const float* __restrict__ ws, float* __restrict__ R0,
                                                   size_t rstride){
  float* Rb = R0 + (size_t)blockIdx.y*rstride;
  const unsigned short* KH = (const unsigned short*)(Rb + R_H);
  const unsigned short* KL = (const unsigned short*)(Rb + R_H + 2097152);
  float2* Tc = (float2*)(Rb + R_SCR);
  const unsigned int* PK = (const unsigned int*)(ws + OFF_PACK);
  const float2* tw1 = (const float2*)(ws + OFF_TW1);
  __shared__ unsigned int Bth[128][20], Btl[128][20];
  int tid = threadIdx.x;
  int lane = tid & 63, wid = tid >> 6;
  int wr = (wid>>1)*64, wc = (wid&1)*64;
  int lr = lane & 15, lk = lane >> 4;
  int row = blockIdx.x;
  f32x4 aR[4][4] = {}, aI[4][4] = {};
  int bc = tid & 127, grp = tid >> 7;
  for (int kt = 0; kt < 4; kt++){
    #pragma unroll
    for (int p=0;p<8;p++){
      int kp = grp*8 + p;
      int a = kt*32 + 2*kp;
      size_t o0 = (size_t)row*HWSZ + a*128 + bc;
      Bth[bc][kp] = (unsigned)KH[o0] | ((unsigned)KH[o0+128] << 16);
      Btl[bc][kp] = (unsigned)KL[o0] | ((unsigned)KL[o0+128] << 16);
    }
    __syncthreads();
    short8 bh[4], bl[4];
    #pragma unroll
    for (int j=0;j<4;j++){
      bh[j] = *(const short8*)&Bth[wc + j*16 + lr][lk*4];
      bl[j] = *(const short8*)&Btl[wc + j*16 + lr][lk*4];
    }
    #pragma unroll
    for (int i=0;i<4;i++){
      int off = (wr + i*16 + lr)*64 + kt*16 + lk*4;
      short8 ahR = ld8g(PK + TDA_RH + off), alR = ld8g(PK + TDA_RL + off);
      short8 ahI = ld8g(PK + TDA_IH + off), alI = ld8g(PK + TDA_IL + off);
      #pragma unroll
      for (int j=0;j<4;j++){
        aR[i][j] = __builtin_amdgcn_mfma_f32_16x16x32_bf16(ahR, bh[j], aR[i][j], 0,0,0);
        aR[i][j] = __builtin_amdgcn_mfma_f32_16x16x32_bf16(ahR, bl[j], aR[i][j], 0,0,0);
        aR[i][j] = __builtin_amdgcn_mfma_f32_16x16x32_bf16(alR, bh[j], aR[i][j], 0,0,0);
        aI[i][j] = __builtin_amdgcn_mfma_f32_16x16x32_bf16(ahI, bh[j], aI[i][j], 0,0,0);
        aI[i][j] = __builtin_amdgcn_mfma_f32_16x16x32_bf16(ahI, bl[j], aI[i][j], 0,0,0);
        aI[i][j] = __builtin_amdgcn_mfma_f32_16x16x32_bf16(alI, bh[j], aI[i][j], 0,0,0);
      }
    }
    __syncthreads();
  }
  #pragma unroll
  for (int i=0;i<4;i++)
    #pragma unroll
    for (int e=0;e<4;e++){
      int m = wr + i*16 + lk*4 + e;     // f0
      #pragma unroll
      for (int j=0;j<4;j++){
        int col = wc + j*16 + lr;       // b2
        float2 t = tw1[m*128 + col];
        float r = aR[i][j][e], im = aI[i][j][e];
        Tc[(size_t)m*32768 + row*128 + col] = make_float2(r*t.x - im*t.y, r*t.y + im*t.x);
      }
    }
}

// ---------------- FFT stage 2 (MFMA, in-place fp32): grid (256, zb) ----------------
__global__ __launch_bounds__(256) void fft2_mfma_k(const float* __restrict__ ws, float* __restrict__ R0,
                                                   size_t rstride){
  float* Rb = R0 + (size_t)blockIdx.y*rstride;
  float2* TU = (float2*)(Rb + R_SCR);
  const unsigned int* PK = (const unsigned int*)(ws + OFF_PACK);
  const float2* tw2 = (const float2*)(ws + OFF_TW2);
  __shared__ unsigned int ARh[128][20], ARl[128][20], AIh[128][20], AIl[128][20];
  int tid = threadIdx.x;
  int lane = tid & 63, wid = tid >> 6;
  int wr = (wid>>1)*64, wc = (wid&1)*64;
  int lr = lane & 15, lk = lane >> 4;
  int m0 = blockIdx.x*128;
  f32x4 aR[4][4] = {}, aI[4][4] = {};
  const float* Tf = (const float*)TU;
  for (int kt = 0; kt < 4; kt++){
    #pragma unroll
    for (int s=0;s<8;s++){
      int id = tid + s*256;
      int r = id >> 4, kp = id & 15;
      int k = kt*32 + 2*kp;
      float4 v = *(const float4*)&Tf[((size_t)(m0+r)*128 + k)*2];
      ARh[r][kp] = pk_hi(v.x, v.z); ARl[r][kp] = pk_lo(v.x, v.z);
      AIh[r][kp] = pk_hi(v.y, v.w); AIl[r][kp] = pk_lo(v.y, v.w);
    }
    __syncthreads();
    short8 ahR[4], alR[4], ahI[4], alI[4];
    #pragma unroll
    for (int i=0;i<4;i++){
      int ar = wr + i*16 + lr;
      ahR[i] = *(const short8*)&ARh[ar][lk*4];
      alR[i] = *(const short8*)&ARl[ar][lk*4];
      ahI[i] = *(const short8*)&AIh[ar][lk*4];
      alI[i] = *(const short8*)&AIl[ar][lk*4];
    }
    #pragma unroll
    for (int j=0;j<4;j++){
      int boff = (wc + j*16 + lr)*64 + kt*16 + lk*4;
      short8 bhR = ld8g(PK + STB_RH + boff), blR = ld8g(PK + STB_RL + boff);
      short8 bhI = ld8g(PK + STB_IH + boff), blI = ld8g(PK + STB_IL + boff);
      short8 bhN = ld8g(PK + STB_NIH + boff), blN = ld8g(PK + STB_NIL + boff);
      #pragma unroll
      for (int i=0;i<4;i++){
        aR[i][j] = __builtin_amdgcn_mfma_f32_16x16x32_bf16(ahR[i], bhR, aR[i][j], 0,0,0);
        aR[i][j] = __builtin_amdgcn_mfma_f32_16x16x32_bf16(ahR[i], blR, aR[i][j], 0,0,0);
        aR[i][j] = __builtin_amdgcn_mfma_f32_16x16x32_bf16(alR[i], bhR, aR[i][j], 0,0,0);
        aR[i][j] = __builtin_amdgcn_mfma_f32_16x16x32_bf16(ahI[i], bhN, aR[i][j], 0,0,0);
        aR[i][j] = __builtin_amdgcn_mfma_f32_16x16x32_bf16(ahI[i], blN, aR[i][j], 0,0,0);
        aR[i][j] = __builtin_amdgcn_mfma_f32_16x16x32_bf16(alI[i], bhN, aR[i][j], 0,0,0);
        aI[i][j] = __builtin_amdgcn_mfma_f32_16x16x32_bf16(ahR[i], bhI, aI[i][j], 0,0,0);
        aI[i][j] = __builtin_amdgcn_mfma_f32_16x16x32_bf16(ahR[i], blI, aI[i][j], 0,0,0);
        aI[i][j] = __builtin_amdgcn_mfma_f32_16x16x32_bf16(alR[i], bhI, aI[i][j], 0,0,0);
        aI[i][j] = __builtin_amdgcn_mfma_f32_16x16x32_bf16(ahI[i], bhR, aI[i][j], 0,0,0);
        aI[i][j] = __builtin_amdgcn_mfma_f32_16x16x32_bf16(ahI[i], blR, aI[i][j], 0,0,0);
        aI[i][j] = __builtin_amdgcn_mfma_f32_16x16x32_bf16(alI[i], bhR, aI[i][j], 0,0,0);
      }
    }
    __syncthreads();
  }
  #pragma unroll
  for (int i=0;i<4;i++)
    #pragma unroll
    for (int e=0;e<4;e++){
      int m = m0 + wr + i*16 + lk*4 + e;
      int f0 = m >> 8;
      #pragma unroll
      for (int j=0;j<4;j++){
        int col = wc + j*16 + lr;
        float2 t = tw2[f0*128 + col];
        float r = aR[i][j][e], im = aI[i][j][e];
        TU[(size_t)m*128 + col] = make_float2(r*t.x - im*t.y, r*t.y + im*t.x);
      }
    }
}

// ---------------- FFT stage 3 (MFMA): reads fp32 U, writes Hn packed bf16 hi/lo ----------------
__global__ __launch_bounds__(256) void fft3_mfma_k(const float* __restrict__ ws, float* __restrict__ R0,
                                                   size_t rstride){
  float* Rb = R0 + (size_t)blockIdx.y*rstride;
  const float2* U = (const float2*)(Rb + R_SCR);
  unsigned short* HHo = (unsigned short*)(Rb + R_SCR + HNOFF);
  unsigned short* HLo = (unsigned short*)(Rb + R_SCR + HNOFF + 2097152);
  const unsigned int* PK = (const unsigned int*)(ws + OFF_PACK);
  __shared__ unsigned int BRh[128][20], BRl[128][20], BIh[128][20], BIl[128][20];
  int tid = threadIdx.x;
  int lane = tid & 63, wid = tid >> 6;
  int wr = (wid>>1)*64, wc = (wid&1)*64;
  int lr = lane & 15, lk = lane >> 4;
  int brow = blockIdx.x;                // d row 0..255
  f32x4 ac[4][4] = {};
  int bc = tid & 127, grp = tid >> 7;
  for (int kt = 0; kt < 4; kt++){
    #pragma unroll
    for (int p=0;p<8;p++){
      int kp = grp*8 + p;
      int k = kt*32 + 2*kp;
      float2 v0 = U[((size_t)k*256 + brow)*128 + bc];
      float2 v1 = U[((size_t)(k+1)*256 + brow)*128 + bc];
      BRh[bc][kp] = pk_hi(v0.x, v1.x); BRl[bc][kp] = pk_lo(v0.x, v1.x);
      BIh[bc][kp] = pk_hi(v0.y, v1.y); BIl[bc][kp] = pk_lo(v0.y, v1.y);
    }
    __syncthreads();
    short8 ahR[4], alR[4], ahI[4], alI[4];
    #pragma unroll
    for (int i=0;i<4;i++){
      int off = (wr + i*16 + lr)*64 + kt*16 + lk*4;
      ahR[i] = ld8g(PK + ETA_RH + off); alR[i] = ld8g(PK + ETA_RL + off);
      ahI[i] = ld8g(PK + ETA_IH + off); alI[i] = ld8g(PK + ETA_IL + off);
    }
    #pragma unroll
    for (int j=0;j<4;j++){
      int col = wc + j*16 + lr;
      short8 bhR = *(const short8*)&BRh[col][lk*4];
      short8 blR = *(const short8*)&BRl[col][lk*4];
      short8 bhI = *(const short8*)&BIh[col][lk*4];
      short8 blI = *(const short8*)&BIl[col][lk*4];
      #pragma unroll
      for (int i=0;i<4;i++){
        ac[i][j] = __builtin_amdgcn_mfma_f32_16x16x32_bf16(ahR[i], bhI, ac[i][j], 0,0,0);
        ac[i][j] = __builtin_amdgcn_mfma_f32_16x16x32_bf16(ahR[i], blI, ac[i][j], 0,0,0);
        ac[i][j] = __builtin_amdgcn_mfma_f32_16x16x32_bf16(alR[i], bhI, ac[i][j], 0,0,0);
        ac[i][j] = __builtin_amdgcn_mfma_f32_16x16x32_bf16(ahI[i], bhR, ac[i][j], 0,0,0);
        ac[i][j] = __builtin_amdgcn_mfma_f32_16x16x32_bf16(ahI[i], blR, ac[i][j], 0,0,0);
        ac[i][j] = __builtin_amdgcn_mfma_f32_16x16x32_bf16(alI[i], bhR, ac[i][j], 0,0,0);
      }
    }
    __syncthreads();
  }
  #pragma unroll
  for (int i=0;i<4;i++)
    #pragma unroll
    for (int e=0;e<4;e++){
      int m = wr + i*16 + lk*4 + e;     // u
      #pragma unroll
      for (int j=0;j<4;j++){
        int col = wc + j*16 + lr;       // r
        float v = ac[i][j][e];
        unsigned u = __float_as_uint(v);
        size_t o = (size_t)brow*HWSZ + m*128 + col;
        HHo[o] = (unsigned short)(u >> 16);
        HLo[o] = b16rn(v - __uint_as_float(u & 0xFFFF0000u));
      }
    }
}

// ---------------- P & Ri via LDS-free MFMA over packed planes ----------------
__global__ __launch_bounds__(256) void pri3_k(float* __restrict__ R0, size_t rstride){
  float* Rb = R0 + (size_t)blockIdx.z*rstride;
  int sp = blockIdx.x, head = blockIdx.y;
  const unsigned short* QH = (const unsigned short*)(Rb + R_QKV);
  const unsigned short* QL = (const unsigned short*)(Rb + R_QKV + 2097152);
  const unsigned short* KH = (const unsigned short*)(Rb + R_H);
  const unsigned short* KL = (const unsigned short*)(Rb + R_H + 2097152);
  const unsigned short* HNH = (const unsigned short*)(Rb + R_SCR + HNOFF);
  const unsigned short* HNL = HNH + 2097152*2;
  float* Pp = Rb + R_PP;
  float* Rp = Rb + R_RP;
  int tid = threadIdx.x, lane = tid & 63, wid = tid >> 6;
  int wr = (wid>>1)*32, wc = (wid&1)*32;
  int lr = lane & 15, lk = lane >> 4;
  size_t qoff[2], koff[2];
  #pragma unroll
  for (int i=0;i<2;i++) qoff[i] = (size_t)(head*64 + wr + i*16 + lr)*HWSZ + sp*256 + lk*8;
  #pragma unroll
  for (int j=0;j<2;j++) koff[j] = (size_t)(head*64 + wc + j*16 + lr)*HWSZ + sp*256 + lk*8;
  f32x4 aP[2][2] = {}, aRi[2][2] = {};
  short8 qh[2][2], ql[2][2], k1h[2][2], k1l[2][2], k2h[2][2], k2l[2][2];
#define LDPRI(B,T) { int d = (T)*32; \
    _Pragma("unroll") \
    for (int i=0;i<2;i++){ \
      qh[B][i] = ld8s(QH + qoff[i] + d); \
      ql[B][i] = ld8s(QL + qoff[i] + d); } \
    _Pragma("unroll") \
    for (int j=0;j<2;j++){ \
      k1h[B][j] = ld8s(KH + koff[j] + d); \
      k1l[B][j] = ld8s(KL + koff[j] + d); \
      k2h[B][j] = ld8s(HNH + koff[j] + d); \
      k2l[B][j] = ld8s(HNL + koff[j] + d); } }
  LDPRI(0,0);
  #pragma unroll
  for (int kt = 0; kt < 8; kt++){
    int cur = kt & 1;
    if (kt < 7) LDPRI(cur^1, kt+1);
    #pragma unroll
    for (int i=0;i<2;i++)
      #pragma unroll
      for (int j=0;j<2;j++){
        aP[i][j]  = __builtin_amdgcn_mfma_f32_16x16x32_bf16(qh[cur][i], k1h[cur][j], aP[i][j], 0,0,0);
        aP[i][j]  = __builtin_amdgcn_mfma_f32_16x16x32_bf16(qh[cur][i], k1l[cur][j], aP[i][j], 0,0,0);
        aP[i][j]  = __builtin_amdgcn_mfma_f32_16x16x32_bf16(ql[cur][i], k1h[cur][j], aP[i][j], 0,0,0);
        aRi[i][j] = __builtin_amdgcn_mfma_f32_16x16x32_bf16(qh[cur][i], k2h[cur][j], aRi[i][j], 0,0,0);
        aRi[i][j] = __builtin_amdgcn_mfma_f32_16x16x32_bf16(qh[cur][i], k2l[cur][j], aRi[i][j], 0,0,0);
        aRi[i][j] = __builtin_amdgcn_mfma_f32_16x16x32_bf16(ql[cur][i], k2h[cur][j], aRi[i][j], 0,0,0);
      }
  }
#undef LDPRI
  size_t obase = ((size_t)(sp*4 + head)) << 12;
  #pragma unroll
  for (int i=0;i<2;i++)
    #pragma unroll
    for (int e=0;e<4;e++){
      int row = wr + i*16 + lk*4 + e;
      #pragma unroll
      for (int j=0;j<2;j++){
        int col = wc + j*16 + lr;
        size_t o = obase + (size_t)row*64 + col;
        Pp[o] = aP[i][j][e];
        Rp[o] = aRi[i][j][e];
      }
    }
}

// ---------------- split reduce + dw stat fold ----------------
__global__ __launch_bounds__(256) void red_k(float* __restrict__ R0, size_t rstride){
  float* Rb = R0 + (size_t)blockIdx.y*rstride;
  const float* Pp = Rb + R_PP;
  const float* Rp = Rb + R_RP;
  float* Ps = Rb + R_PS;
  float* Rs = Rb + R_RS;
  int tid = threadIdx.x;
  #pragma unroll
  for (int rep=0; rep<2; rep++){
    int g = blockIdx.x*512 + rep*256 + tid;
    int head = g >> 12, loc = g & 4095;
    float p = 0.f, ri = 0.f;
    for (int sp=0; sp<64; sp++){
      size_t o = ((size_t)(sp*4+head)<<12) + loc;
      p += Pp[o]; ri += Rp[o];
    }
    Ps[g] = p; Rs[g] = ri;
  }
  if (blockIdx.x == 0){
    const float* part = Rb + R_DWP;
    for (int ch = tid; ch < CH3; ch += 256){
      float s=0.f, sa=0.f, sq=0.f;
      #pragma unroll
      for (int sl=0; sl<4; sl++){
        s  += part[ch*4+sl];
        sa += part[3072+ch*4+sl];
        sq += part[6144+ch*4+sl];
      }
      Rb[R_SSUM+ch]=s; Rb[R_SALT+ch]=sa; Rb[R_SSQ+ch]=sq;
    }
  }
}

// ---------------- attn build ----------------
__global__ __launch_bounds__(256) void attn_build_k(const float* __restrict__ ws, float* __restrict__ R0,
                                                    size_t rstride, const float* __restrict__ temperature){
  float* Rb = R0 + (size_t)blockIdx.y*rstride;
  const float* Ps   = Rb + R_PS;
  const float* Rs   = Rb + R_RS;
  const float* ssum = Rb + R_SSUM;
  const float* salt = Rb + R_SALT;
  const float* ssq  = Rb + R_SSQ;
  float* attn = Rb + R_ATTN;
  const float* hmg  = ws + OFF_HM;
  __shared__ float Rn[64][65], Ril[64][65], hm[64];
  int head = blockIdx.x;
  int tid = threadIdx.x;
  if (tid < 64) hm[tid] = hmg[tid];
  for (int t=0;t<16;t++){
    int idx = tid + t*256; int c = idx>>6, d = idx&63;
    float P = Ps[head*4096 + idx], Ri = Rs[head*4096 + idx];
    int qch = head*64 + c;
    int kch = 256 + head*64 + d;
    float qs=ssum[qch], qa=salt[qch], qn=fmaxf(sqrtf(ssq[qch]), 1e-12f);
    float ks=ssum[kch], ka=salt[kch], kn=fmaxf(sqrtf(ssq[kch]), 1e-12f);
    float Rr = 0.5f*(16384.0f*P + qs*ks + qa*ka);
    float sc = 1.0f/(qn*kn);
    Rn[c][d]  = Rr*sc;
    Ril[c][d] = Ri*sc;
  }
  __syncthreads();
  float tmp2 = temperature[(head+2)&3];
  for (int t=0;t<16;t++){
    int idx = tid + t*256; int c = idx>>6, e = idx&63;
    float s = Rn[c][e];
    #pragma unroll 8
    for (int d=0; d<64; d++) s += Ril[c][d]*hm[(e-d)&63];
    attn[((size_t)head<<12) + (size_t)(c*64+e)] = s*tmp2;
  }
}

// ---------------- nested top-k masked softmax ----------------
__global__ __launch_bounds__(64) void topk_k(float* __restrict__ R0, size_t rstride,
                                             const float* __restrict__ attn_w){
  float* Rb = R0 + (size_t)blockIdx.y*rstride;
  const float* attn = Rb + R_ATTN;
  float* Acomb = Rb + R_ACOMB;
  int blk = blockIdx.x;
  int tid = threadIdx.x;
  __shared__ float row[64];
  float v = attn[(size_t)blk*64 + tid];
  row[tid] = v;
  __syncthreads();
  int rank = 0; float vmax = -1e30f;
  for (int l=0;l<64;l++){
    float w = row[l];
    if (w > v || (w == v && l < tid)) rank++;
    vmax = fmaxf(vmax, w);
  }
  float e = expf(v - vmax);
  const int kks[4] = {32,42,48,51};
  float denom[4];
  #pragma unroll
  for (int i=0;i<4;i++){
    float x = (rank < kks[i]) ? e : 0.0f;
    #pragma unroll
    for (int off=32; off; off>>=1) x += __shfl_xor(x, off);
    denom[i] = x;
  }
  float wgt = 0.f;
  #pragma unroll
  for (int i=0;i<4;i++) if (rank < kks[i]) wgt += attn_w[i] / denom[i];
  Acomb[(size_t)blk*64 + tid] = e * wgt;
}

// ---------------- out_head = A_comb @ v, packed output ----------------
__global__ __launch_bounds__(256) void av_k(float* __restrict__ R0, size_t rstride){
  float* Rb = R0 + (size_t)blockIdx.z*rstride;
  const float* Acomb = Rb + R_ACOMB;
  unsigned int* BqH = (unsigned int*)(Rb + R_H);
  unsigned int* BqL = BqH + 2097152;
  int head = blockIdx.y;
  int n0 = blockIdx.x*64;
  const float* Vb = Rb + R_QKV + (size_t)(512 + head*64)*HWSZ;
  __shared__ float As[64][65], Bs[16][65];
  int tid=threadIdx.x, tx=tid&15, ty=tid>>4;
  for (int t=0;t<16;t++){ int idx=tid+t*256; As[idx>>6][idx&63] = Acomb[((size_t)head<<12)+idx]; }
  __syncthreads();
  float acc[4][4]={};
  for (int k0=0;k0<64;k0+=16){
    #pragma unroll
    for (int i=0;i<4;i++){ int id=tid+i*256; int nn=id&63, k=id>>6;
      Bs[k][nn] = Vb[(size_t)(k0+k)*HWSZ + n0+nn]; }
    __syncthreads();
    #pragma unroll
    for (int k=0;k<16;k++){
      float a[4], bv[4];
      #pragma unroll
      for (int i=0;i<4;i++) a[i]=As[ty*4+i][k0+k];
      #pragma unroll
      for (int j=0;j<4;j++) bv[j]=Bs[k][tx*4+j];
      #pragma unroll
      for (int i=0;i<4;i++)
        #pragma unroll
        for (int j=0;j<4;j++) acc[i][j] += a[i]*bv[j];
    }
    __syncthreads();
  }
  int kpa = head*32 + ty*2;
  int kba = kpa >> 2, qa = kpa & 3;
  int kpb = kpa + 1;
  int kbb = kpb >> 2, qb = kpb & 3;
  #pragma unroll
  for (int j=0;j<4;j++){
    int n = n0 + tx*4 + j;
    BqH[((size_t)kba*HWSZ + n)*4 + qa] = pk_hi(acc[0][j], acc[1][j]);
    BqL[((size_t)kba*HWSZ + n)*4 + qa] = pk_lo(acc[0][j], acc[1][j]);
    BqH[((size_t)kbb*HWSZ + n)*4 + qb] = pk_hi(acc[2][j], acc[3][j]);
    BqL[((size_t)kbb*HWSZ + n)*4 + qb] = pk_lo(acc[2][j], acc[3][j]);
  }
}

extern "C" void kernel_launch(void* const* d_in, const int* in_sizes, int n_in,
                              void* d_out, int out_size, void* d_ws, size_t ws_size,
                              hipStream_t stream) {
  const float* x     = (const float*)d_in[0];
  const float* gn_w  = (const float*)d_in[1];
  const float* gn_b  = (const float*)d_in[2];
  const float* w_qkv = (const float*)d_in[3];
  const float* w_dw  = (const float*)d_in[4];
  const float* w_out = (const float*)d_in[5];
  const float* b_out = (const float*)d_in[6];
  const float* temperature = (const float*)d_in[7];
  const float* attn_w = (const float*)d_in[8];
  float* out = (float*)d_out;
  float* ws  = (float*)d_ws;
  unsigned int* AW = (unsigned int*)(ws + OFF_AW);
  float* R0 = ws + SHARED_END;
  const size_t CHW = (size_t)NC*HWSZ;

  size_t need2 = (SHARED_END + 2*RSTRIDE)*sizeof(float);
  size_t need4 = (SHARED_END + 4*RSTRIDE)*sizeof(float);
  int zb = (ws_size >= need4) ? 4 : (ws_size >= need2) ? 2 : 1;

  init_tables_k<<<64,256,0,stream>>>(ws);
  wpack_k<<<512,256,0,stream>>>(w_qkv, w_out, AW);
  gn_part_k<<<1024,256,0,stream>>>(x, (float2*)(ws+OFF_GNP));
  gn_fin_k<<<1,128,0,stream>>>((const float2*)(ws+OFF_GNP), gn_w, gn_b,
                               ws+OFF_SCALE, ws+OFF_SHIFT);

  for (int b0 = 0; b0 < 4; b0 += zb){
    packx_k<<<dim3(64,32,zb),256,0,stream>>>(x + (size_t)b0*CHW, ws+OFF_SCALE+b0*NC,
                                             ws+OFF_SHIFT+b0*NC, R0, RSTRIDE);
    gemm_pk<<<dim3(128,6,zb),256,0,stream>>>(AW+AWQ_H, AW+AWQ_L,
                                             (unsigned int*)(R0+R_H), (unsigned int*)(R0+R_H)+2097152,
                                             nullptr, R0+R_SCR, RSTRIDE, RSTRIDE);
    dwconv_tiled_k<<<dim3(3072,zb),256,0,stream>>>(R0, RSTRIDE, w_dw);
    fft1_mfma_k<<<dim3(256,zb),256,0,stream>>>(ws, R0, RSTRIDE);
    fft2_mfma_k<<<dim3(256,zb),256,0,stream>>>(ws, R0, RSTRIDE);
    fft3_mfma_k<<<dim3(256,zb),256,0,stream>>>(ws, R0, RSTRIDE);
    pri3_k<<<dim3(64,4,zb),256,0,stream>>>(R0, RSTRIDE);
    red_k<<<dim3(32,zb),256,0,stream>>>(R0, RSTRIDE);
    attn_build_k<<<dim3(4,zb),256,0,stream>>>(ws, R0, RSTRIDE, temperature);
    topk_k<<<dim3(256,zb),64,0,stream>>>(R0, RSTRIDE, attn_w);
    av_k<<<dim3(256,4,zb),256,0,stream>>>(R0, RSTRIDE);
    gemm_pk<<<dim3(128,2,zb),256,0,stream>>>(AW+AWO_H, AW+AWO_L,
                                             (unsigned int*)(R0+R_H), (unsigned int*)(R0+R_H)+2097152,
                                             b_out, out + (size_t)b0*CHW, RSTRIDE, CHW);
  }
}